// Round 9
// baseline (24.495 us; speedup 1.0000x reference)
//
#include <hip/hip_runtime.h>
#include <float.h>

#define NPTS 4096
#define NB   8

typedef __bf16 bf16x8 __attribute__((ext_vector_type(8)));
typedef float  f32x16 __attribute__((ext_vector_type(16)));

__device__ __forceinline__ float min3f(float a, float b, float c) {
    return fminf(fminf(a, b), c);   // clang fuses to v_min3_f32
}

__device__ __forceinline__ void split_bf(float v, __bf16& hi, __bf16& lo) {
    hi = (__bf16)v;
    lo = (__bf16)(v - (float)hi);
}

// ---------------- fused: full-row min per col chunk, one kernel --------------
// grid (16, 16): blockIdx.x = 256-col chunk, blockIdx.y = bdir = b*2+dir.
// dir0: rows=gts, cols=preds; dir1 swapped. Block = 512 threads (8 waves);
// wave w owns rows [w*512, w*512+512) as 16 i-blocks of 32 -> per-col min over
// ALL 4096 rows completes in-block (LDS cross-wave min). Block then sums its
// 256 col-mins and atomicAdd's one partial into out[b] (32 commutative f32
// adds per batch — cheap, unlike round 7's device-fence storm).
// Split-bf16 rank-13 K-expansion, one v_mfma_f32_32x32x16_bf16 per 32x32 tile
// (slot map identical to rounds 5-8, absmax ~0).
__global__ void __launch_bounds__(512, 2) chamfer_fused(
    const float* __restrict__ preds,
    const float* __restrict__ gts,
    float* __restrict__ out)
{
    __shared__ __align__(16) __bf16 Btab[2][256][8];   // 8 KB
    __shared__ float pmLds[8][256];                    // 8 KB
    __shared__ float red[256];                         // 1 KB

    const int chunk = blockIdx.x;
    const int bdir  = blockIdx.y;
    const int b = bdir >> 1, dir = bdir & 1;

    const float* rows = ((dir == 0) ? gts   : preds) + (size_t)b * NPTS * 3;
    const float* cols = ((dir == 0) ? preds : gts)   + (size_t)b * NPTS * 3;

    const int tid  = threadIdx.x;
    const int lane = tid & 63;
    const int w    = tid >> 6;
    const __bf16 one = (__bf16)1.0f, zero = (__bf16)0.0f;

    // stage B table: 256 cols, split-bf16 of (-2x,-2y,-2z) and h
    if (tid < 256) {
        const int c = tid;
        const float* p = cols + (size_t)(chunk * 256 + c) * 3;
        const float x = p[0], y = p[1], z = p[2];
        const float h = x * x + y * y + z * z;
        __bf16 uh, ul, vh, vl, wh, wl, hh, hl;
        split_bf(-2.0f * x, uh, ul);
        split_bf(-2.0f * y, vh, vl);
        split_bf(-2.0f * z, wh, wl);
        split_bf(h, hh, hl);
        bf16x8 b0, b1;
        b0[0] = uh; b0[1] = ul; b0[2] = uh; b0[3] = vh;
        b0[4] = vl; b0[5] = vh; b0[6] = wh; b0[7] = wl;
        b1[0] = wh; b1[1] = one; b1[2] = one; b1[3] = hh;
        b1[4] = hl; b1[5] = zero; b1[6] = zero; b1[7] = zero;
        *(bf16x8*)&Btab[0][c][0] = b0;
        *(bf16x8*)&Btab[1][c][0] = b1;
    }

    // A fragments: 16 i-blocks x 32 rows per wave; lane half picks k0-7/k8-15
    bf16x8 afr[16];
    const int rbase = w * 512;
    #pragma unroll
    for (int ib = 0; ib < 16; ++ib) {
        const float* g = rows + (size_t)(rbase + ib * 32 + (lane & 31)) * 3;
        const float x = g[0], y = g[1], z = g[2];
        const float h = x * x + y * y + z * z;
        __bf16 xh, xl, yh, yl, zh, zl, hh, hl;
        split_bf(x, xh, xl);
        split_bf(y, yh, yl);
        split_bf(z, zh, zl);
        split_bf(h, hh, hl);
        bf16x8 a;
        if (lane < 32) {
            a[0] = xh; a[1] = xh; a[2] = xl; a[3] = yh;
            a[4] = yh; a[5] = yl; a[6] = zh; a[7] = zh;
        } else {
            a[0] = zl; a[1] = hh; a[2] = hl; a[3] = one;
            a[4] = one; a[5] = zero; a[6] = zero; a[7] = zero;
        }
        afr[ib] = a;
    }
    __syncthreads();

    f32x16 zc = 0.0f;    // C = 0 (everything folded into K)

    #pragma unroll
    for (int jt = 0; jt < 8; ++jt) {
        const bf16x8 bfr = *(const bf16x8*)&Btab[lane >> 5][jt * 32 + (lane & 31)][0];
        float pmin = FLT_MAX;
        #pragma unroll
        for (int ib = 0; ib < 16; ++ib) {
            f32x16 d = __builtin_amdgcn_mfma_f32_32x32x16_bf16(afr[ib], bfr, zc, 0, 0, 0);
            const float m0 = min3f(d[0],  d[1],  d[2]);
            const float m1 = min3f(d[3],  d[4],  d[5]);
            const float m2 = min3f(d[6],  d[7],  d[8]);
            const float m3 = min3f(d[9],  d[10], d[11]);
            const float m4 = min3f(d[12], d[13], d[14]);
            const float mm = min3f(min3f(m0, m1, m2), fminf(m3, m4), d[15]);
            pmin = fminf(pmin, mm);
        }
        // combine the two lane-half row-groups -> 512-row min per col
        pmin = fminf(pmin, __shfl_xor(pmin, 32, 64));
        if (lane < 32) pmLds[w][jt * 32 + (lane & 31)] = pmin;
    }
    __syncthreads();

    // cross-wave (8 row-bands of 512) min -> full 4096-row min, then col-sum
    if (tid < 256) {
        float m = pmLds[0][tid];
        #pragma unroll
        for (int q = 1; q < 8; ++q) m = fminf(m, pmLds[q][tid]);
        red[tid] = m;
    }
    __syncthreads();
    #pragma unroll
    for (int off = 128; off >= 1; off >>= 1) {
        if (tid < off) red[tid] += red[tid + off];
        __syncthreads();
    }
    if (tid == 0) atomicAdd(&out[b], red[0]);
}

extern "C" void kernel_launch(void* const* d_in, const int* in_sizes, int n_in,
                              void* d_out, int out_size, void* d_ws, size_t ws_size,
                              hipStream_t stream)
{
    const float* preds = (const float*)d_in[0];
    const float* gts   = (const float*)d_in[1];
    float* out = (float*)d_out;

    hipMemsetAsync(d_out, 0, NB * sizeof(float), stream);
    chamfer_fused<<<dim3(16, 16), 512, 0, stream>>>(preds, gts, out);
}